// Round 11
// baseline (53.299 us; speedup 1.0000x reference)
//
#include <hip/hip_runtime.h>

#define NN   2048
#define EE   65536
#define EDIM 64
#define LL   5
#define TPK2 262144            // threads in gather kernel (256 x 1024)
#define NP   ((size_t)NN * NN) // 4,194,304 pairs

// Kernel 1: dotsT[l][e] = sum_d edge_attr[e][d] * edge_vector[l][d]  (fp16, transposed)
__global__ __launch_bounds__(256) void dots_kernel(
    const float* __restrict__ edge_attr,
    const float* __restrict__ edge_vector,
    _Float16* __restrict__ dotsT) {
  const int lane = threadIdx.x & 63;
  const int wib  = threadIdx.x >> 6;
  const int dg   = lane & 15;
  const int es   = lane >> 4;
  const int e    = blockIdx.x * 16 + wib * 4 + es;

  const float4 a = *(const float4*)(edge_attr + e * EDIM + dg * 4);
  float d[LL];
#pragma unroll
  for (int l = 0; l < LL; ++l) {
    const float4 ev = *(const float4*)(edge_vector + l * EDIM + dg * 4);
    d[l] = a.x * ev.x + a.y * ev.y + a.z * ev.z + a.w * ev.w;
  }
#pragma unroll
  for (int s = 1; s <= 8; s <<= 1) {
#pragma unroll
    for (int l = 0; l < LL; ++l) d[l] += __shfl_xor(d[l], s, 64);
  }
  if (dg < LL) {
    const float dv = (dg == 0) ? d[0] : (dg == 1) ? d[1] : (dg == 2) ? d[2]
                   : (dg == 3) ? d[3] : d[4];
    dotsT[dg * EE + e] = (_Float16)dv;
  }
}

// Kernel 2: transpose pre-pass. Reads ept ONCE (the unavoidable uncoalesced
// read), emits l-major packed u16 ids (adrT[l][pair]) + packed 4-bit counts.
// This removes all cross-pass index state from the gather kernel — the
// R6-R10 wall (compiler rematerializing/spilling 40 regs of indices into
// 5x uncoalesced re-reads at the 64-VGPR cap for 1024-thread WGs).
__global__ __launch_bounds__(256) void transpose_kernel(
    const int* __restrict__ ept,
    unsigned short* __restrict__ adrT,   // [LL][NP]
    unsigned* __restrict__ cnts) {       // [NP/4], 4x4-bit counts in low 16b
  const int t = blockIdx.x * 256 + threadIdx.x;   // 4-pair group id
  const int4* p = (const int4*)(ept + (size_t)t * 20);
  int raw[20];
#pragma unroll
  for (int q = 0; q < 5; ++q) {
    const int4 v = p[q];
    raw[q * 4 + 0] = v.x; raw[q * 4 + 1] = v.y;
    raw[q * 4 + 2] = v.z; raw[q * 4 + 3] = v.w;
  }
  unsigned cw = 0u;
  unsigned a[20];                        // u16 value per (l, pair j)
#pragma unroll
  for (int j = 0; j < 4; ++j) {
#pragma unroll
    for (int l = 0; l < LL; ++l) {
      const int id = raw[j * 5 + l];
      a[l * 4 + j] = (id < 0) ? 0u : (unsigned)id;   // invalid -> 0 (corrected later)
      cw += ((id >= 0) ? 1u : 0u) << (j * 4);
    }
  }
#pragma unroll
  for (int l = 0; l < LL; ++l) {
    uint2 w;
    w.x = a[l * 4 + 0] | (a[l * 4 + 1] << 16);
    w.y = a[l * 4 + 2] | (a[l * 4 + 3] << 16);
    ((uint2*)(adrT + (size_t)l * NP))[t] = w;
  }
  cnts[t] = cw;
}

// Kernel 3: streaming gather. Live state = sum[16] + 2 count words (~35 regs,
// safely under the 64-VGPR cap). Per pass: stage plane l (128 KB LDS), read
// this pass's adr slice via 4 coalesced uint2 loads, gather 16 ds_read_u16,
// accumulate. Invalid slots hit tab[0]; suffix-sum correction cancels them.
__global__ __launch_bounds__(1024) void gather_kernel(
    const unsigned short* __restrict__ adrT,
    const unsigned* __restrict__ cnts,
    const _Float16* __restrict__ dotsT,
    float* __restrict__ out) {
  __shared__ __align__(16) unsigned short tab[EE];   // exactly 128 KB
  const int tid = blockIdx.x * 1024 + threadIdx.x;   // 0..TPK2-1

  // counts: 4 group-words -> two packed 4-bit x8 registers
  const unsigned w0 = cnts[0 * TPK2 + tid];
  const unsigned w1 = cnts[1 * TPK2 + tid];
  const unsigned w2 = cnts[2 * TPK2 + tid];
  const unsigned w3 = cnts[3 * TPK2 + tid];
  const unsigned cp0 = w0 | (w1 << 16);
  const unsigned cp1 = w2 | (w3 << 16);

  float sum[16];
#pragma unroll
  for (int k = 0; k < 16; ++k) sum[k] = 0.f;
  float t0v[LL];

  const char* tabb = (const char*)tab;

#pragma unroll
  for (int l = 0; l < LL; ++l) {
    __syncthreads();  // previous pass's reads done before overwrite
    const float4* src = (const float4*)(dotsT + (size_t)l * EE);
    float4* dst = (float4*)tab;
#pragma unroll
    for (int r = 0; r < 8; ++r)
      dst[r * 1024 + threadIdx.x] = src[r * 1024 + threadIdx.x];
    __syncthreads();
    t0v[l] = (float)*(const _Float16*)tabb;          // broadcast read
    const uint2* ap = (const uint2*)(adrT + (size_t)l * NP);
#pragma unroll
    for (int g = 0; g < 4; ++g) {
      const uint2 a = ap[g * TPK2 + tid];            // coalesced 8 B/lane
      const unsigned e0 = a.x & 0xffffu, e1 = a.x >> 16;
      const unsigned e2 = a.y & 0xffffu, e3 = a.y >> 16;
      sum[g * 4 + 0] += (float)*(const _Float16*)(tabb + 2 * e0);
      sum[g * 4 + 1] += (float)*(const _Float16*)(tabb + 2 * e1);
      sum[g * 4 + 2] += (float)*(const _Float16*)(tabb + 2 * e2);
      sum[g * 4 + 3] += (float)*(const _Float16*)(tabb + 2 * e3);
    }
  }

  // Suffix sums of tab[0] per pass: S[m] = sum_{l>=m} t0v[l].
  const float S4 = t0v[4];
  const float S3 = S4 + t0v[3];
  const float S2 = S3 + t0v[2];
  const float S1 = S2 + t0v[1];
  const float S0 = S1 + t0v[0];

#pragma unroll
  for (int g = 0; g < 4; ++g) {
    const size_t gid = (size_t)g * TPK2 + (size_t)tid;
    float rr[4];
#pragma unroll
    for (int j = 0; j < 4; ++j) {
      const int k = g * 4 + j;
      const unsigned cnt = (((k < 8) ? cp0 : cp1) >> ((k & 7) * 4)) & 15u;
      const float corr = (cnt == 5) ? 0.f
                       : (cnt == 4) ? S4
                       : (cnt == 3) ? S3
                       : (cnt == 2) ? S2
                       : (cnt == 1) ? S1 : S0;
      rr[j] = (sum[k] - corr) / ((float)cnt + 1e-10f);  // cnt==0 -> 0
    }
    ((float4*)out)[gid] = make_float4(rr[0], rr[1], rr[2], rr[3]);
  }
}

// Fallback (ws too small): R6's proven 5-pass kernel (~41 us total).
__global__ __launch_bounds__(1024) void pairs_fallback(
    const int* __restrict__ ept,
    const _Float16* __restrict__ dotsT,
    float* __restrict__ out) {
  __shared__ __align__(16) unsigned short tab[EE + 8];
  const int tid = blockIdx.x * 1024 + threadIdx.x;

  int adr[80];
  unsigned cp0 = 0u, cp1 = 0u;
#pragma unroll
  for (int g = 0; g < 4; ++g) {
    const size_t gid = (size_t)g * TPK2 + (size_t)tid;
    const int4* p = (const int4*)(ept + gid * 20);
#pragma unroll
    for (int q = 0; q < 5; ++q) {
      const int4 v = p[q];
#pragma unroll
      for (int jj = 0; jj < 4; ++jj) {
        const int si = q * 4 + jj;
        const int k  = g * 4 + si / 5;
        const int id = (jj == 0) ? v.x : (jj == 1) ? v.y : (jj == 2) ? v.z : v.w;
        adr[g * 20 + si] = (id < 0) ? (EE * 2) : (id * 2);
        const unsigned m = (id >= 0) ? 1u : 0u;
        if (k < 8) cp0 += m << ((k & 7) * 4); else cp1 += m << ((k & 7) * 4);
      }
    }
  }
  float sum[16];
#pragma unroll
  for (int k = 0; k < 16; ++k) sum[k] = 0.f;
  const char* tabb = (const char*)tab;
  if (threadIdx.x == 0) tab[EE] = 0;
#pragma unroll
  for (int l = 0; l < LL; ++l) {
    __syncthreads();
    const float4* src = (const float4*)(dotsT + (size_t)l * EE);
    float4* dst = (float4*)tab;
#pragma unroll
    for (int r = 0; r < 8; ++r)
      dst[r * 1024 + threadIdx.x] = src[r * 1024 + threadIdx.x];
    __syncthreads();
#pragma unroll
    for (int k = 0; k < 16; ++k)
      sum[k] += (float)*(const _Float16*)(tabb + adr[k * 5 + l]);
  }
#pragma unroll
  for (int g = 0; g < 4; ++g) {
    const size_t gid = (size_t)g * TPK2 + (size_t)tid;
    float rr[4];
#pragma unroll
    for (int j = 0; j < 4; ++j) {
      const int k = g * 4 + j;
      const unsigned cnt = (((k < 8) ? cp0 : cp1) >> ((k & 7) * 4)) & 15u;
      rr[j] = sum[k] / ((float)cnt + 1e-10f);
    }
    ((float4*)out)[gid] = make_float4(rr[0], rr[1], rr[2], rr[3]);
  }
}

extern "C" void kernel_launch(void* const* d_in, const int* in_sizes, int n_in,
                              void* d_out, int out_size, void* d_ws, size_t ws_size,
                              hipStream_t stream) {
  const float* edge_attr   = (const float*)d_in[1];
  const float* edge_vector = (const float*)d_in[2];
  const int*   ept         = (const int*)d_in[3];
  float* out = (float*)d_out;

  const size_t dots_bytes = (size_t)LL * EE * 2;   //   655,360
  const size_t adr_bytes  = (size_t)LL * NP * 2;   // 41,943,040
  const size_t cnt_bytes  = NP;                    //  4,194,304

  _Float16* dotsT      = (_Float16*)d_ws;
  unsigned short* adrT = (unsigned short*)((char*)d_ws + dots_bytes);
  unsigned* cnts       = (unsigned*)((char*)d_ws + dots_bytes + adr_bytes);

  dots_kernel<<<EE / 16, 256, 0, stream>>>(edge_attr, edge_vector, dotsT);

  if (ws_size >= dots_bytes + adr_bytes + cnt_bytes) {
    transpose_kernel<<<(int)(NP / 4 / 256), 256, 0, stream>>>(ept, adrT, cnts);
    gather_kernel<<<256, 1024, 0, stream>>>(adrT, cnts, dotsT, out);
  } else {
    pairs_fallback<<<256, 1024, 0, stream>>>(ept, dotsT, out);
  }
}